// Round 6
// baseline (1052.052 us; speedup 1.0000x reference)
//
#include <hip/hip_runtime.h>
#include <hip/hip_fp16.h>

#define N_NODES 100000
#define N_EDGES 1600000
#define F 64
#define NCLS 16
#define K1 8
#define NB 391      // node buckets: bucket = row >> 8  -> ceil(100000/256)
#define BCAP 6144   // per-bucket capacity; mean 4096, sigma~64 -> +32 sigma headroom

using f16x8 = __attribute__((ext_vector_type(8))) _Float16;
using f32x4 = __attribute__((ext_vector_type(4))) float;

// ---------------- pass A: degree count + bucket scatter ----------------
// bucket writes go to atomically-advancing cursors -> ~391 sequential write
// streams -> full line utilization (vs 64B/edge random scatter).
__global__ void k_bucket(const int* __restrict__ ei, int* __restrict__ deg,
                         int* __restrict__ bcur, int2* __restrict__ bk) {
    int e = blockIdx.x * blockDim.x + threadIdx.x;
    if (e >= N_EDGES) return;
    int r = ei[e], c = ei[N_EDGES + e];
    if (r == c) return;
    atomicAdd(&deg[r], 1);
    int b = r >> 8;
    int p = atomicAdd(&bcur[b], 1);
    bk[(size_t)b * BCAP + p] = make_int2(r, c);
}

__global__ void k_dinv(const int* __restrict__ deg, float* __restrict__ dinv) {
    int i = blockIdx.x * blockDim.x + threadIdx.x;
    if (i >= N_NODES) return;
    int d = deg[i];
    dinv[i] = d > 0 ? rsqrtf((float)d) : 0.f;
}

// ---------------- exclusive scan (rowptr) ----------------
__global__ void k_scan1(const int* __restrict__ deg, int* __restrict__ rowptr, int* __restrict__ bsum) {
    __shared__ int sd[256];
    int tid = threadIdx.x;
    int base = blockIdx.x * 1024 + tid * 4;
    int v[4];
#pragma unroll
    for (int j = 0; j < 4; j++) {
        int idx = base + j;
        v[j] = (idx < N_NODES) ? deg[idx] : 0;
    }
    int s = v[0] + v[1] + v[2] + v[3];
    sd[tid] = s;
    __syncthreads();
    for (int d = 1; d < 256; d <<= 1) {
        int t = (tid >= d) ? sd[tid - d] : 0;
        __syncthreads();
        sd[tid] += t;
        __syncthreads();
    }
    int excl = sd[tid] - s;
    if (tid == 255) bsum[blockIdx.x] = sd[255];
    int run = excl;
#pragma unroll
    for (int j = 0; j < 4; j++) {
        int idx = base + j;
        if (idx < N_NODES) rowptr[idx] = run;
        run += v[j];
    }
}

__global__ void k_scan2(int* __restrict__ bsum, int* __restrict__ rowptr, int nblk) {
    if (threadIdx.x == 0 && blockIdx.x == 0) {
        int acc = 0;
        for (int b = 0; b < nblk; b++) { int t = bsum[b]; bsum[b] = acc; acc += t; }
        rowptr[N_NODES] = acc;
    }
}

__global__ void k_scan3(int* __restrict__ rowptr, const int* __restrict__ bsum) {
    int tid = threadIdx.x;
    int base = blockIdx.x * 1024 + tid * 4;
    int off = bsum[blockIdx.x];
#pragma unroll
    for (int j = 0; j < 4; j++) {
        int idx = base + j;
        if (idx < N_NODES) rowptr[idx] += off;
    }
}

// ---------------- pass B: bucket -> CSR (packed col, weight) ----------------
// block b drains bucket b; CSR writes confined to a ~32KB contiguous window.
__global__ __launch_bounds__(256) void k_csr(const int2* __restrict__ bk,
                                             const int* __restrict__ bcur,
                                             const int* __restrict__ rowptr,
                                             int* __restrict__ cursor,
                                             const float* __restrict__ dinv,
                                             int2* __restrict__ csr_ew) {
    int b = blockIdx.x;
    int cnt = bcur[b];
    const int2* src = bk + (size_t)b * BCAP;
    for (int i = threadIdx.x; i < cnt; i += 256) {
        int2 rc = src[i];
        float w = -dinv[rc.x] * dinv[rc.y];
        int p = rowptr[rc.x] + atomicAdd(&cursor[rc.x], 1);
        csr_ew[p] = make_int2(rc.y, __float_as_int(w));
    }
}

// ---------------- x fp32 -> fp16 ----------------
__global__ void k_cvt(const float* __restrict__ x, __half* __restrict__ t0) {
    int i = blockIdx.x * blockDim.x + threadIdx.x;
    int base = i * 4;
    if (base >= N_NODES * F) return;
    float4 v = *(const float4*)&x[base];
    __half2 a = __floats2half2_rn(v.x, v.y);
    __half2 b = __floats2half2_rn(v.z, v.w);
    *(__half2*)&t0[base] = a;
    *(__half2*)&t0[base + 2] = b;
}

// ---------------- W1 -> fp16 B-fragment layout ----------------
__global__ void k_prepW(const float* __restrict__ W1, __half* __restrict__ Wf) {
    int t = blockIdx.x * blockDim.x + threadIdx.x;
    if (t >= K1 * 2 * 4 * 64) return;
    int lane = t & 63;
    int cb = (t >> 6) & 3;
    int fg = (t >> 8) & 1;
    int kidx = t >> 9;
    int col = cb * 16 + (lane & 15);
    int kbase = fg * 32 + (lane >> 4) * 8;
    f16x8 v;
#pragma unroll
    for (int j = 0; j < 8; j++)
        v[j] = (_Float16)W1[kidx * 4096 + (kbase + j) * 64 + col];
    *(f16x8*)(Wf + (size_t)t * 8) = v;
}

// ---------------- propagation (round-4 version): dst = alpha*(L_hat@src) - beta*prev ----------------
__global__ __launch_bounds__(256) void k_prop(const int* __restrict__ rowptr,
                                              const int2* __restrict__ csr_ew,
                                              const __half* __restrict__ src,
                                              const __half* __restrict__ prev,
                                              __half* __restrict__ dst,
                                              float alpha, float beta) {
    int wid = (int)((blockIdx.x * blockDim.x + threadIdx.x) >> 6);
    int lane = threadIdx.x & 63;
    if (wid >= N_NODES) return;
    int beg = rowptr[wid], end = rowptr[wid + 1];

    float acc0 = 0.f, acc1 = 0.f, acc2 = 0.f, acc3 = 0.f;

    for (int cb = beg; cb < end; cb += 64) {
        int n = end - cb;
        if (n > 64) n = 64;
        int2 e = make_int2(0, 0);
        if (lane < n) e = csr_ew[cb + lane];

        int j = 0;
        for (; j + 7 < n; j += 8) {
            int cc[8];
            float ww[8];
#pragma unroll
            for (int u = 0; u < 8; u++) {
                cc[u] = __shfl(e.x, j + u, 64);
                ww[u] = __int_as_float(__shfl(e.y, j + u, 64));
            }
            float vv[8];
#pragma unroll
            for (int u = 0; u < 8; u++)
                vv[u] = __half2float(src[(size_t)cc[u] * F + lane]);
            acc0 = fmaf(ww[0], vv[0], acc0);
            acc1 = fmaf(ww[1], vv[1], acc1);
            acc2 = fmaf(ww[2], vv[2], acc2);
            acc3 = fmaf(ww[3], vv[3], acc3);
            acc0 = fmaf(ww[4], vv[4], acc0);
            acc1 = fmaf(ww[5], vv[5], acc1);
            acc2 = fmaf(ww[6], vv[6], acc2);
            acc3 = fmaf(ww[7], vv[7], acc3);
        }
        for (; j + 3 < n; j += 4) {
            int cc[4];
            float ww[4];
#pragma unroll
            for (int u = 0; u < 4; u++) {
                cc[u] = __shfl(e.x, j + u, 64);
                ww[u] = __int_as_float(__shfl(e.y, j + u, 64));
            }
            float vv[4];
#pragma unroll
            for (int u = 0; u < 4; u++)
                vv[u] = __half2float(src[(size_t)cc[u] * F + lane]);
            acc0 = fmaf(ww[0], vv[0], acc0);
            acc1 = fmaf(ww[1], vv[1], acc1);
            acc2 = fmaf(ww[2], vv[2], acc2);
            acc3 = fmaf(ww[3], vv[3], acc3);
        }
        for (; j < n; j++) {
            int c0 = __shfl(e.x, j, 64);
            float w0 = __int_as_float(__shfl(e.y, j, 64));
            acc0 = fmaf(w0, __half2float(src[(size_t)c0 * F + lane]), acc0);
        }
    }

    float res = alpha * ((acc0 + acc1) + (acc2 + acc3));
    if (beta != 0.f) res -= beta * __half2float(prev[(size_t)wid * F + lane]);
    dst[(size_t)wid * F + lane] = __float2half(res);
}

// ---------------- fused MFMA: y = softmax(relu(sum_k Tk@W1k + b1) @ W2 + b2) ----------------
__global__ __launch_bounds__(256) void k_fused_mfma(const __half* __restrict__ T,
                                                    const __half* __restrict__ Wf,
                                                    const float* __restrict__ b1,
                                                    const float* __restrict__ W2,
                                                    const float* __restrict__ b2,
                                                    float* __restrict__ y) {
    __shared__ float Ht[64][65];
    __shared__ float W2l[64 * 16];
    __shared__ float b2l[16];
    int tid = threadIdx.x;
    int lane = tid & 63;
    int w = tid >> 6;
    int ln15 = lane & 15;
    int lg = lane >> 4;
    int base = blockIdx.x * 64;

    for (int j = tid; j < 64 * 16; j += 256) W2l[j] = W2[j];
    if (tid < 16) b2l[tid] = b2[tid];

    int nd = base + (w << 4) + ln15;
    if (nd > N_NODES - 1) nd = N_NODES - 1;  // clamp: garbage rows, stores guarded

    f32x4 acc0 = {0.f, 0.f, 0.f, 0.f};
    f32x4 acc1 = {0.f, 0.f, 0.f, 0.f};
    f32x4 acc2 = {0.f, 0.f, 0.f, 0.f};
    f32x4 acc3 = {0.f, 0.f, 0.f, 0.f};

    for (int s = 0; s < 16; s++) {
        int kidx = s >> 1;
        int fg = s & 1;
        f16x8 a = *(const f16x8*)(T + ((size_t)kidx * N_NODES + nd) * F + fg * 32 + lg * 8);
        const __half* wb = Wf + ((size_t)((kidx * 2 + fg) * 4) * 64 + lane) * 8;
        f16x8 b0 = *(const f16x8*)(wb);
        f16x8 b1f = *(const f16x8*)(wb + 64 * 8);
        f16x8 b2f = *(const f16x8*)(wb + 128 * 8);
        f16x8 b3f = *(const f16x8*)(wb + 192 * 8);
        acc0 = __builtin_amdgcn_mfma_f32_16x16x32_f16(a, b0, acc0, 0, 0, 0);
        acc1 = __builtin_amdgcn_mfma_f32_16x16x32_f16(a, b1f, acc1, 0, 0, 0);
        acc2 = __builtin_amdgcn_mfma_f32_16x16x32_f16(a, b2f, acc2, 0, 0, 0);
        acc3 = __builtin_amdgcn_mfma_f32_16x16x32_f16(a, b3f, acc3, 0, 0, 0);
    }

    int hrow = (w << 4) + (lg << 2);
    {
        float bb0 = b1[0 * 16 + ln15];
        float bb1 = b1[1 * 16 + ln15];
        float bb2 = b1[2 * 16 + ln15];
        float bb3 = b1[3 * 16 + ln15];
#pragma unroll
        for (int r = 0; r < 4; r++) {
            float h0 = acc0[r] + bb0;
            float h1 = acc1[r] + bb1;
            float h2 = acc2[r] + bb2;
            float h3 = acc3[r] + bb3;
            Ht[hrow + r][0 * 16 + ln15] = h0 > 0.f ? h0 : 0.f;
            Ht[hrow + r][1 * 16 + ln15] = h1 > 0.f ? h1 : 0.f;
            Ht[hrow + r][2 * 16 + ln15] = h2 > 0.f ? h2 : 0.f;
            Ht[hrow + r][3 * 16 + ln15] = h3 > 0.f ? h3 : 0.f;
        }
    }
    __syncthreads();

    int node = tid >> 2;
    int cg = tid & 3;
    int gnode = base + node;
    if (gnode >= N_NODES) return;
    float l0 = b2l[cg * 4 + 0], l1 = b2l[cg * 4 + 1], l2 = b2l[cg * 4 + 2], l3 = b2l[cg * 4 + 3];
    for (int f = 0; f < 64; f++) {
        float h = Ht[node][f];
        l0 = fmaf(h, W2l[f * 16 + cg * 4 + 0], l0);
        l1 = fmaf(h, W2l[f * 16 + cg * 4 + 1], l1);
        l2 = fmaf(h, W2l[f * 16 + cg * 4 + 2], l2);
        l3 = fmaf(h, W2l[f * 16 + cg * 4 + 3], l3);
    }
    float m = fmaxf(fmaxf(l0, l1), fmaxf(l2, l3));
    m = fmaxf(m, __shfl_xor(m, 1, 64));
    m = fmaxf(m, __shfl_xor(m, 2, 64));
    float e0 = expf(l0 - m), e1 = expf(l1 - m), e2 = expf(l2 - m), e3 = expf(l3 - m);
    float s = e0 + e1 + e2 + e3;
    s += __shfl_xor(s, 1, 64);
    s += __shfl_xor(s, 2, 64);
    float inv = 1.f / s;
    float4 o = make_float4(e0 * inv, e1 * inv, e2 * inv, e3 * inv);
    *(float4*)&y[(size_t)gnode * 16 + cg * 4] = o;
}

// ---------------- launch ----------------

extern "C" void kernel_launch(void* const* d_in, const int* in_sizes, int n_in,
                              void* d_out, int out_size, void* d_ws, size_t ws_size,
                              hipStream_t stream) {
    const float* x  = (const float*)d_in[0];
    const int*   ei = (const int*)d_in[1];
    const float* W1 = (const float*)d_in[2];
    const float* b1 = (const float*)d_in[3];
    const float* W2 = (const float*)d_in[4];
    const float* b2 = (const float*)d_in[5];
    float* y = (float*)d_out;

    char* p = (char*)d_ws;
    auto alloc = [&](size_t bytes) {
        char* q = p;
        p += (bytes + 255) & ~(size_t)255;
        return q;
    };
    int*   deg    = (int*)alloc((size_t)N_NODES * 4);
    float* dinv   = (float*)alloc((size_t)N_NODES * 4);
    int*   rowptr = (int*)alloc((size_t)(N_NODES + 1) * 4);
    int*   bsum   = (int*)alloc(128 * 4);
    int*   cursor = (int*)alloc((size_t)N_NODES * 4);
    int*   bcur   = (int*)alloc((size_t)NB * 4);
    int2*  csr_ew = (int2*)alloc((size_t)N_EDGES * 8);
    __half* T     = (__half*)alloc((size_t)K1 * N_NODES * F * 2);
    __half* Wf    = (__half*)alloc((size_t)K1 * 2 * 4 * 64 * 8 * 2);

    // bucket buffer (19.2 MB) aliases T: dead before k_cvt/k_prop write T.
    int2* bk = (int2*)T;

    hipMemsetAsync(deg, 0, (size_t)N_NODES * 4, stream);
    hipMemsetAsync(cursor, 0, (size_t)N_NODES * 4, stream);
    hipMemsetAsync(bcur, 0, (size_t)NB * 4, stream);

    int eb = (N_EDGES + 255) / 256;
    int nb = (N_NODES + 255) / 256;
    k_bucket<<<eb, 256, 0, stream>>>(ei, deg, bcur, bk);
    k_dinv<<<nb, 256, 0, stream>>>(deg, dinv);
    int nblk = (N_NODES + 1023) / 1024;
    k_scan1<<<nblk, 256, 0, stream>>>(deg, rowptr, bsum);
    k_scan2<<<1, 64, 0, stream>>>(bsum, rowptr, nblk);
    k_scan3<<<nblk, 256, 0, stream>>>(rowptr, bsum);
    k_csr<<<NB, 256, 0, stream>>>(bk, bcur, rowptr, cursor, dinv, csr_ew);
    k_prepW<<<16, 256, 0, stream>>>(W1, Wf);

    const size_t TSZ = (size_t)N_NODES * F;
    __half* Tk[K1];
    for (int k = 0; k < K1; k++) Tk[k] = T + (size_t)k * TSZ;

    k_cvt<<<(N_NODES * F / 4 + 255) / 256, 256, 0, stream>>>(x, Tk[0]);

    int prop_blocks = (N_NODES + 3) / 4;
    k_prop<<<prop_blocks, 256, 0, stream>>>(rowptr, csr_ew, Tk[0], Tk[0], Tk[1], 1.f, 0.f);
    for (int k = 2; k < K1; k++)
        k_prop<<<prop_blocks, 256, 0, stream>>>(rowptr, csr_ew, Tk[k - 1], Tk[k - 2], Tk[k], 2.f, 1.f);

    int gemm_blocks = (N_NODES + 63) / 64;
    k_fused_mfma<<<gemm_blocks, 256, 0, stream>>>(T, Wf, b1, W2, b2, y);
}

// Round 7
// 554.164 us; speedup vs baseline: 1.8984x; 1.8984x over previous
//
#include <hip/hip_runtime.h>
#include <hip/hip_fp16.h>

#define N_NODES 100000
#define N_EDGES 1600000
#define F 64
#define NCLS 16
#define K1 8

using f16x8 = __attribute__((ext_vector_type(8))) _Float16;
using f32x4 = __attribute__((ext_vector_type(4))) float;

// ---------------- degree / normalization ----------------

__global__ void k_deg(const int* __restrict__ ei, int* __restrict__ deg) {
    int e = blockIdx.x * blockDim.x + threadIdx.x;
    if (e >= N_EDGES) return;
    int r = ei[e], c = ei[N_EDGES + e];
    if (r != c) atomicAdd(&deg[r], 1);
}

__global__ void k_dinv(const int* __restrict__ deg, float* __restrict__ dinv) {
    int i = blockIdx.x * blockDim.x + threadIdx.x;
    if (i >= N_NODES) return;
    int d = deg[i];
    dinv[i] = d > 0 ? rsqrtf((float)d) : 0.f;
}

// ---------------- exclusive scan (rowptr) ----------------
__global__ void k_scan1(const int* __restrict__ deg, int* __restrict__ rowptr, int* __restrict__ bsum) {
    __shared__ int sd[256];
    int tid = threadIdx.x;
    int base = blockIdx.x * 1024 + tid * 4;
    int v[4];
#pragma unroll
    for (int j = 0; j < 4; j++) {
        int idx = base + j;
        v[j] = (idx < N_NODES) ? deg[idx] : 0;
    }
    int s = v[0] + v[1] + v[2] + v[3];
    sd[tid] = s;
    __syncthreads();
    for (int d = 1; d < 256; d <<= 1) {
        int t = (tid >= d) ? sd[tid - d] : 0;
        __syncthreads();
        sd[tid] += t;
        __syncthreads();
    }
    int excl = sd[tid] - s;
    if (tid == 255) bsum[blockIdx.x] = sd[255];
    int run = excl;
#pragma unroll
    for (int j = 0; j < 4; j++) {
        int idx = base + j;
        if (idx < N_NODES) rowptr[idx] = run;
        run += v[j];
    }
}

__global__ void k_scan2(int* __restrict__ bsum, int* __restrict__ rowptr, int nblk) {
    if (threadIdx.x == 0 && blockIdx.x == 0) {
        int acc = 0;
        for (int b = 0; b < nblk; b++) { int t = bsum[b]; bsum[b] = acc; acc += t; }
        rowptr[N_NODES] = acc;
    }
}

__global__ void k_scan3(int* __restrict__ rowptr, const int* __restrict__ bsum) {
    int tid = threadIdx.x;
    int base = blockIdx.x * 1024 + tid * 4;
    int off = bsum[blockIdx.x];
#pragma unroll
    for (int j = 0; j < 4; j++) {
        int idx = base + j;
        if (idx < N_NODES) rowptr[idx] += off;
    }
}

// ---------------- CSR fill: packed (col, weight_bits) ----------------
__global__ void k_fill(const int* __restrict__ ei, const float* __restrict__ dinv,
                       const int* __restrict__ rowptr, int* __restrict__ cursor,
                       int2* __restrict__ csr_ew) {
    int e = blockIdx.x * blockDim.x + threadIdx.x;
    if (e >= N_EDGES) return;
    int r = ei[e], c = ei[N_EDGES + e];
    if (r == c) return;
    int p = rowptr[r] + atomicAdd(&cursor[r], 1);
    float w = -dinv[r] * dinv[c];
    csr_ew[p] = make_int2(c, __float_as_int(w));
}

// ---------------- x fp32 -> fp16 ----------------
__global__ void k_cvt(const float* __restrict__ x, __half* __restrict__ t0) {
    int i = blockIdx.x * blockDim.x + threadIdx.x;
    int base = i * 4;
    if (base >= N_NODES * F) return;
    float4 v = *(const float4*)&x[base];
    __half2 a = __floats2half2_rn(v.x, v.y);
    __half2 b = __floats2half2_rn(v.z, v.w);
    *(__half2*)&t0[base] = a;
    *(__half2*)&t0[base + 2] = b;
}

// ---------------- W1 -> fp16 B-fragment layout ----------------
__global__ void k_prepW(const float* __restrict__ W1, __half* __restrict__ Wf) {
    int t = blockIdx.x * blockDim.x + threadIdx.x;
    if (t >= K1 * 2 * 4 * 64) return;
    int lane = t & 63;
    int cb = (t >> 6) & 3;
    int fg = (t >> 8) & 1;
    int kidx = t >> 9;
    int col = cb * 16 + (lane & 15);
    int kbase = fg * 32 + (lane >> 4) * 8;
    f16x8 v;
#pragma unroll
    for (int j = 0; j < 8; j++)
        v[j] = (_Float16)W1[kidx * 4096 + (kbase + j) * 64 + col];
    *(f16x8*)(Wf + (size_t)t * 8) = v;
}

// ---------------- propagation: 2 nodes per wave, 16 outstanding gathers ----------------
// lanes 0-31 hold node A's edge records, lanes 32-63 node B's; all 64 lanes
// compute feature `lane` for BOTH nodes. Padded slots have w=0 (gather row 0, L1-hot).
__global__ __launch_bounds__(256) void k_prop(const int* __restrict__ rowptr,
                                              const int2* __restrict__ csr_ew,
                                              const __half* __restrict__ src,
                                              const __half* __restrict__ prev,
                                              __half* __restrict__ dst,
                                              float alpha, float beta) {
    int wpair = (int)((blockIdx.x * blockDim.x + threadIdx.x) >> 6);
    int lane = threadIdx.x & 63;
    int nA = wpair * 2;
    if (nA >= N_NODES) return;
    int nB = nA + 1;
    bool hasB = (nB < N_NODES);
    int begA = rowptr[nA], endA = rowptr[nA + 1];
    int begB = hasB ? rowptr[nB] : 0;
    int endB = hasB ? rowptr[nB + 1] : 0;
    int hl = lane & 31;

    float accA0 = 0.f, accA1 = 0.f, accA2 = 0.f, accA3 = 0.f;
    float accB0 = 0.f, accB1 = 0.f, accB2 = 0.f, accB3 = 0.f;

    int cbA = begA, cbB = begB;
    while (cbA < endA || cbB < endB) {
        int nAc = endA - cbA; nAc = nAc < 0 ? 0 : (nAc > 32 ? 32 : nAc);
        int nBc = endB - cbB; nBc = nBc < 0 ? 0 : (nBc > 32 ? 32 : nBc);
        int2 e = make_int2(0, 0);
        if (lane < 32) {
            if (hl < nAc) e = csr_ew[cbA + hl];
        } else {
            if (hl < nBc) e = csr_ew[cbB + hl];
        }
        int nmax = nAc > nBc ? nAc : nBc;
        for (int j = 0; j < nmax; j += 8) {
            int ccA[8], ccB[8];
            float wwA[8], wwB[8];
#pragma unroll
            for (int u = 0; u < 8; u++) {
                ccA[u] = __shfl(e.x, j + u, 64);
                wwA[u] = __int_as_float(__shfl(e.y, j + u, 64));
                ccB[u] = __shfl(e.x, 32 + j + u, 64);
                wwB[u] = __int_as_float(__shfl(e.y, 32 + j + u, 64));
            }
            float vvA[8], vvB[8];
#pragma unroll
            for (int u = 0; u < 8; u++) {
                vvA[u] = __half2float(src[(size_t)ccA[u] * F + lane]);
                vvB[u] = __half2float(src[(size_t)ccB[u] * F + lane]);
            }
            accA0 = fmaf(wwA[0], vvA[0], accA0);
            accA1 = fmaf(wwA[1], vvA[1], accA1);
            accA2 = fmaf(wwA[2], vvA[2], accA2);
            accA3 = fmaf(wwA[3], vvA[3], accA3);
            accB0 = fmaf(wwB[0], vvB[0], accB0);
            accB1 = fmaf(wwB[1], vvB[1], accB1);
            accB2 = fmaf(wwB[2], vvB[2], accB2);
            accB3 = fmaf(wwB[3], vvB[3], accB3);
            accA0 = fmaf(wwA[4], vvA[4], accA0);
            accA1 = fmaf(wwA[5], vvA[5], accA1);
            accA2 = fmaf(wwA[6], vvA[6], accA2);
            accA3 = fmaf(wwA[7], vvA[7], accA3);
            accB0 = fmaf(wwB[4], vvB[4], accB0);
            accB1 = fmaf(wwB[5], vvB[5], accB1);
            accB2 = fmaf(wwB[6], vvB[6], accB2);
            accB3 = fmaf(wwB[7], vvB[7], accB3);
        }
        cbA += nAc;
        cbB += nBc;
    }

    float resA = alpha * ((accA0 + accA1) + (accA2 + accA3));
    if (beta != 0.f) resA -= beta * __half2float(prev[(size_t)nA * F + lane]);
    dst[(size_t)nA * F + lane] = __float2half(resA);
    if (hasB) {
        float resB = alpha * ((accB0 + accB1) + (accB2 + accB3));
        if (beta != 0.f) resB -= beta * __half2float(prev[(size_t)nB * F + lane]);
        dst[(size_t)nB * F + lane] = __float2half(resB);
    }
}

// ---------------- fused MFMA: y = softmax(relu(sum_k Tk@W1k + b1) @ W2 + b2) ----------------
__global__ __launch_bounds__(256) void k_fused_mfma(const __half* __restrict__ T,
                                                    const __half* __restrict__ Wf,
                                                    const float* __restrict__ b1,
                                                    const float* __restrict__ W2,
                                                    const float* __restrict__ b2,
                                                    float* __restrict__ y) {
    __shared__ float Ht[64][65];
    __shared__ float W2l[64 * 16];
    __shared__ float b2l[16];
    int tid = threadIdx.x;
    int lane = tid & 63;
    int w = tid >> 6;
    int ln15 = lane & 15;
    int lg = lane >> 4;
    int base = blockIdx.x * 64;

    for (int j = tid; j < 64 * 16; j += 256) W2l[j] = W2[j];
    if (tid < 16) b2l[tid] = b2[tid];

    int nd = base + (w << 4) + ln15;
    if (nd > N_NODES - 1) nd = N_NODES - 1;  // clamp: garbage rows, stores guarded

    f32x4 acc0 = {0.f, 0.f, 0.f, 0.f};
    f32x4 acc1 = {0.f, 0.f, 0.f, 0.f};
    f32x4 acc2 = {0.f, 0.f, 0.f, 0.f};
    f32x4 acc3 = {0.f, 0.f, 0.f, 0.f};

    for (int s = 0; s < 16; s++) {
        int kidx = s >> 1;
        int fg = s & 1;
        f16x8 a = *(const f16x8*)(T + ((size_t)kidx * N_NODES + nd) * F + fg * 32 + lg * 8);
        const __half* wb = Wf + ((size_t)((kidx * 2 + fg) * 4) * 64 + lane) * 8;
        f16x8 b0 = *(const f16x8*)(wb);
        f16x8 b1f = *(const f16x8*)(wb + 64 * 8);
        f16x8 b2f = *(const f16x8*)(wb + 128 * 8);
        f16x8 b3f = *(const f16x8*)(wb + 192 * 8);
        acc0 = __builtin_amdgcn_mfma_f32_16x16x32_f16(a, b0, acc0, 0, 0, 0);
        acc1 = __builtin_amdgcn_mfma_f32_16x16x32_f16(a, b1f, acc1, 0, 0, 0);
        acc2 = __builtin_amdgcn_mfma_f32_16x16x32_f16(a, b2f, acc2, 0, 0, 0);
        acc3 = __builtin_amdgcn_mfma_f32_16x16x32_f16(a, b3f, acc3, 0, 0, 0);
    }

    int hrow = (w << 4) + (lg << 2);
    {
        float bb0 = b1[0 * 16 + ln15];
        float bb1 = b1[1 * 16 + ln15];
        float bb2 = b1[2 * 16 + ln15];
        float bb3 = b1[3 * 16 + ln15];
#pragma unroll
        for (int r = 0; r < 4; r++) {
            float h0 = acc0[r] + bb0;
            float h1 = acc1[r] + bb1;
            float h2 = acc2[r] + bb2;
            float h3 = acc3[r] + bb3;
            Ht[hrow + r][0 * 16 + ln15] = h0 > 0.f ? h0 : 0.f;
            Ht[hrow + r][1 * 16 + ln15] = h1 > 0.f ? h1 : 0.f;
            Ht[hrow + r][2 * 16 + ln15] = h2 > 0.f ? h2 : 0.f;
            Ht[hrow + r][3 * 16 + ln15] = h3 > 0.f ? h3 : 0.f;
        }
    }
    __syncthreads();

    int node = tid >> 2;
    int cg = tid & 3;
    int gnode = base + node;
    if (gnode >= N_NODES) return;
    float l0 = b2l[cg * 4 + 0], l1 = b2l[cg * 4 + 1], l2 = b2l[cg * 4 + 2], l3 = b2l[cg * 4 + 3];
    for (int f = 0; f < 64; f++) {
        float h = Ht[node][f];
        l0 = fmaf(h, W2l[f * 16 + cg * 4 + 0], l0);
        l1 = fmaf(h, W2l[f * 16 + cg * 4 + 1], l1);
        l2 = fmaf(h, W2l[f * 16 + cg * 4 + 2], l2);
        l3 = fmaf(h, W2l[f * 16 + cg * 4 + 3], l3);
    }
    float m = fmaxf(fmaxf(l0, l1), fmaxf(l2, l3));
    m = fmaxf(m, __shfl_xor(m, 1, 64));
    m = fmaxf(m, __shfl_xor(m, 2, 64));
    float e0 = expf(l0 - m), e1 = expf(l1 - m), e2 = expf(l2 - m), e3 = expf(l3 - m);
    float s = e0 + e1 + e2 + e3;
    s += __shfl_xor(s, 1, 64);
    s += __shfl_xor(s, 2, 64);
    float inv = 1.f / s;
    float4 o = make_float4(e0 * inv, e1 * inv, e2 * inv, e3 * inv);
    *(float4*)&y[(size_t)gnode * 16 + cg * 4] = o;
}

// ---------------- launch ----------------

extern "C" void kernel_launch(void* const* d_in, const int* in_sizes, int n_in,
                              void* d_out, int out_size, void* d_ws, size_t ws_size,
                              hipStream_t stream) {
    const float* x  = (const float*)d_in[0];
    const int*   ei = (const int*)d_in[1];
    const float* W1 = (const float*)d_in[2];
    const float* b1 = (const float*)d_in[3];
    const float* W2 = (const float*)d_in[4];
    const float* b2 = (const float*)d_in[5];
    float* y = (float*)d_out;

    char* p = (char*)d_ws;
    auto alloc = [&](size_t bytes) {
        char* q = p;
        p += (bytes + 255) & ~(size_t)255;
        return q;
    };
    int*   deg    = (int*)alloc((size_t)N_NODES * 4);
    float* dinv   = (float*)alloc((size_t)N_NODES * 4);
    int*   rowptr = (int*)alloc((size_t)(N_NODES + 1) * 4);
    int*   bsum   = (int*)alloc(128 * 4);
    int*   cursor = (int*)alloc((size_t)N_NODES * 4);
    int2*  csr_ew = (int2*)alloc((size_t)N_EDGES * 8);
    __half* T     = (__half*)alloc((size_t)K1 * N_NODES * F * 2);
    __half* Wf    = (__half*)alloc((size_t)K1 * 2 * 4 * 64 * 8 * 2);

    hipMemsetAsync(deg, 0, (size_t)N_NODES * 4, stream);
    hipMemsetAsync(cursor, 0, (size_t)N_NODES * 4, stream);

    int eb = (N_EDGES + 255) / 256;
    int nb = (N_NODES + 255) / 256;
    k_deg<<<eb, 256, 0, stream>>>(ei, deg);
    k_dinv<<<nb, 256, 0, stream>>>(deg, dinv);
    int nblk = (N_NODES + 1023) / 1024;
    k_scan1<<<nblk, 256, 0, stream>>>(deg, rowptr, bsum);
    k_scan2<<<1, 64, 0, stream>>>(bsum, rowptr, nblk);
    k_scan3<<<nblk, 256, 0, stream>>>(rowptr, bsum);
    k_fill<<<eb, 256, 0, stream>>>(ei, dinv, rowptr, cursor, csr_ew);
    k_prepW<<<16, 256, 0, stream>>>(W1, Wf);

    const size_t TSZ = (size_t)N_NODES * F;
    __half* Tk[K1];
    for (int k = 0; k < K1; k++) Tk[k] = T + (size_t)k * TSZ;

    k_cvt<<<(N_NODES * F / 4 + 255) / 256, 256, 0, stream>>>(x, Tk[0]);

    int npair = (N_NODES + 1) / 2;
    int prop_blocks = (npair + 3) / 4;
    k_prop<<<prop_blocks, 256, 0, stream>>>(rowptr, csr_ew, Tk[0], Tk[0], Tk[1], 1.f, 0.f);
    for (int k = 2; k < K1; k++)
        k_prop<<<prop_blocks, 256, 0, stream>>>(rowptr, csr_ew, Tk[k - 1], Tk[k - 2], Tk[k], 2.f, 1.f);

    int gemm_blocks = (N_NODES + 63) / 64;
    k_fused_mfma<<<gemm_blocks, 256, 0, stream>>>(T, Wf, b1, W2, b2, y);
}

// Round 8
// 540.337 us; speedup vs baseline: 1.9470x; 1.0256x over previous
//
#include <hip/hip_runtime.h>
#include <hip/hip_fp16.h>

#define N_NODES 100000
#define N_EDGES 1600000
#define F 64
#define NCLS 16
#define K1 8
#define BSH 11                 // bucket = row >> 11  (2048 rows)
#define NBK 49                 // ceil(100000 / 2048)
#define BROWS 2048
#define BKCAP 36864            // mean 32768 + 22 sigma

using f16x8 = __attribute__((ext_vector_type(8))) _Float16;
using f32x4 = __attribute__((ext_vector_type(4))) float;

// ---------------- pass A: bucket edges by row-range, LDS-aggregated claiming ----------------
// 1024 edges/block; one global atomic per (block,bucket); contiguous chunk writes.
__global__ __launch_bounds__(256) void k_bucketA(const int* __restrict__ ei,
                                                 int* __restrict__ gcur,
                                                 int2* __restrict__ bk) {
    __shared__ int cnt[64];
    __shared__ int base[64];
    int tid = threadIdx.x;
    if (tid < 64) cnt[tid] = 0;
    __syncthreads();
    int r[4], c[4], b[4], rank[4];
    int e0 = blockIdx.x * 1024;
#pragma unroll
    for (int u = 0; u < 4; u++) {
        int e = e0 + u * 256 + tid;
        b[u] = -1;
        if (e < N_EDGES) {
            r[u] = ei[e];
            c[u] = ei[N_EDGES + e];
            if (r[u] != c[u]) {
                b[u] = r[u] >> BSH;
                rank[u] = atomicAdd(&cnt[b[u]], 1);
            }
        }
    }
    __syncthreads();
    if (tid < NBK) base[tid] = (cnt[tid] > 0) ? atomicAdd(&gcur[tid], cnt[tid]) : 0;
    __syncthreads();
#pragma unroll
    for (int u = 0; u < 4; u++)
        if (b[u] >= 0)
            bk[(size_t)b[u] * BKCAP + base[b[u]] + rank[u]] = make_int2(r[u], c[u]);
}

// ---------------- pass B1: per-bucket degree histogram (no global atomics) ----------------
__global__ __launch_bounds__(256) void k_degB(const int2* __restrict__ bk,
                                              const int* __restrict__ gcur,
                                              int* __restrict__ deg) {
    __shared__ int hist[BROWS];
    int b = blockIdx.x;
    for (int i = threadIdx.x; i < BROWS; i += 256) hist[i] = 0;
    __syncthreads();
    int cnt = gcur[b];
    const int2* src = bk + (size_t)b * BKCAP;
    for (int i = threadIdx.x; i < cnt; i += 256)
        atomicAdd(&hist[src[i].x & (BROWS - 1)], 1);
    __syncthreads();
    int rbase = b << BSH;
    for (int i = threadIdx.x; i < BROWS; i += 256) {
        int gr = rbase + i;
        if (gr < N_NODES) deg[gr] = hist[i];
    }
}

__global__ void k_dinv(const int* __restrict__ deg, float* __restrict__ dinv) {
    int i = blockIdx.x * blockDim.x + threadIdx.x;
    if (i >= N_NODES) return;
    int d = deg[i];
    dinv[i] = d > 0 ? rsqrtf((float)d) : 0.f;
}

// ---------------- exclusive scan (rowptr) ----------------
__global__ void k_scan1(const int* __restrict__ deg, int* __restrict__ rowptr, int* __restrict__ bsum) {
    __shared__ int sd[256];
    int tid = threadIdx.x;
    int base = blockIdx.x * 1024 + tid * 4;
    int v[4];
#pragma unroll
    for (int j = 0; j < 4; j++) {
        int idx = base + j;
        v[j] = (idx < N_NODES) ? deg[idx] : 0;
    }
    int s = v[0] + v[1] + v[2] + v[3];
    sd[tid] = s;
    __syncthreads();
    for (int d = 1; d < 256; d <<= 1) {
        int t = (tid >= d) ? sd[tid - d] : 0;
        __syncthreads();
        sd[tid] += t;
        __syncthreads();
    }
    int excl = sd[tid] - s;
    if (tid == 255) bsum[blockIdx.x] = sd[255];
    int run = excl;
#pragma unroll
    for (int j = 0; j < 4; j++) {
        int idx = base + j;
        if (idx < N_NODES) rowptr[idx] = run;
        run += v[j];
    }
}

__global__ void k_scan2(int* __restrict__ bsum, int* __restrict__ rowptr, int nblk) {
    if (threadIdx.x == 0 && blockIdx.x == 0) {
        int acc = 0;
        for (int b = 0; b < nblk; b++) { int t = bsum[b]; bsum[b] = acc; acc += t; }
        rowptr[N_NODES] = acc;
    }
}

__global__ void k_scan3(int* __restrict__ rowptr, const int* __restrict__ bsum) {
    int tid = threadIdx.x;
    int base = blockIdx.x * 1024 + tid * 4;
    int off = bsum[blockIdx.x];
#pragma unroll
    for (int j = 0; j < 4; j++) {
        int idx = base + j;
        if (idx < N_NODES) rowptr[idx] += off;
    }
}

// ---------------- pass B2: bucket -> CSR, LDS row-cursors, single-XCD window ----------------
__global__ __launch_bounds__(256) void k_fillB(const int2* __restrict__ bk,
                                               const int* __restrict__ gcur,
                                               const int* __restrict__ rowptr,
                                               const float* __restrict__ dinv,
                                               int2* __restrict__ csr_ew) {
    __shared__ int cur[BROWS];
    int b = blockIdx.x;
    for (int i = threadIdx.x; i < BROWS; i += 256) cur[i] = 0;
    __syncthreads();
    int cnt = gcur[b];
    const int2* src = bk + (size_t)b * BKCAP;
    for (int i = threadIdx.x; i < cnt; i += 256) {
        int2 rc = src[i];
        int rank = atomicAdd(&cur[rc.x & (BROWS - 1)], 1);
        float w = -dinv[rc.x] * dinv[rc.y];
        csr_ew[rowptr[rc.x] + rank] = make_int2(rc.y, __float_as_int(w));
    }
}

// ---------------- x fp32 -> fp16 ----------------
__global__ void k_cvt(const float* __restrict__ x, __half* __restrict__ t0) {
    int i = blockIdx.x * blockDim.x + threadIdx.x;
    int base = i * 4;
    if (base >= N_NODES * F) return;
    float4 v = *(const float4*)&x[base];
    __half2 a = __floats2half2_rn(v.x, v.y);
    __half2 b = __floats2half2_rn(v.z, v.w);
    *(__half2*)&t0[base] = a;
    *(__half2*)&t0[base + 2] = b;
}

// ---------------- W1 -> fp16 B-fragment layout ----------------
__global__ void k_prepW(const float* __restrict__ W1, __half* __restrict__ Wf) {
    int t = blockIdx.x * blockDim.x + threadIdx.x;
    if (t >= K1 * 2 * 4 * 64) return;
    int lane = t & 63;
    int cb = (t >> 6) & 3;
    int fg = (t >> 8) & 1;
    int kidx = t >> 9;
    int col = cb * 16 + (lane & 15);
    int kbase = fg * 32 + (lane >> 4) * 8;
    f16x8 v;
#pragma unroll
    for (int j = 0; j < 8; j++)
        v[j] = (_Float16)W1[kidx * 4096 + (kbase + j) * 64 + col];
    *(f16x8*)(Wf + (size_t)t * 8) = v;
}

// ---------------- propagation (round-4 version): dst = alpha*(L_hat@src) - beta*prev ----------------
__global__ __launch_bounds__(256) void k_prop(const int* __restrict__ rowptr,
                                              const int2* __restrict__ csr_ew,
                                              const __half* __restrict__ src,
                                              const __half* __restrict__ prev,
                                              __half* __restrict__ dst,
                                              float alpha, float beta) {
    int wid = (int)((blockIdx.x * blockDim.x + threadIdx.x) >> 6);
    int lane = threadIdx.x & 63;
    if (wid >= N_NODES) return;
    int beg = rowptr[wid], end = rowptr[wid + 1];

    float acc0 = 0.f, acc1 = 0.f, acc2 = 0.f, acc3 = 0.f;

    for (int cb = beg; cb < end; cb += 64) {
        int n = end - cb;
        if (n > 64) n = 64;
        int2 e = make_int2(0, 0);
        if (lane < n) e = csr_ew[cb + lane];

        int j = 0;
        for (; j + 7 < n; j += 8) {
            int cc[8];
            float ww[8];
#pragma unroll
            for (int u = 0; u < 8; u++) {
                cc[u] = __shfl(e.x, j + u, 64);
                ww[u] = __int_as_float(__shfl(e.y, j + u, 64));
            }
            float vv[8];
#pragma unroll
            for (int u = 0; u < 8; u++)
                vv[u] = __half2float(src[(size_t)cc[u] * F + lane]);
            acc0 = fmaf(ww[0], vv[0], acc0);
            acc1 = fmaf(ww[1], vv[1], acc1);
            acc2 = fmaf(ww[2], vv[2], acc2);
            acc3 = fmaf(ww[3], vv[3], acc3);
            acc0 = fmaf(ww[4], vv[4], acc0);
            acc1 = fmaf(ww[5], vv[5], acc1);
            acc2 = fmaf(ww[6], vv[6], acc2);
            acc3 = fmaf(ww[7], vv[7], acc3);
        }
        for (; j + 3 < n; j += 4) {
            int cc[4];
            float ww[4];
#pragma unroll
            for (int u = 0; u < 4; u++) {
                cc[u] = __shfl(e.x, j + u, 64);
                ww[u] = __int_as_float(__shfl(e.y, j + u, 64));
            }
            float vv[4];
#pragma unroll
            for (int u = 0; u < 4; u++)
                vv[u] = __half2float(src[(size_t)cc[u] * F + lane]);
            acc0 = fmaf(ww[0], vv[0], acc0);
            acc1 = fmaf(ww[1], vv[1], acc1);
            acc2 = fmaf(ww[2], vv[2], acc2);
            acc3 = fmaf(ww[3], vv[3], acc3);
        }
        for (; j < n; j++) {
            int c0 = __shfl(e.x, j, 64);
            float w0 = __int_as_float(__shfl(e.y, j, 64));
            acc0 = fmaf(w0, __half2float(src[(size_t)c0 * F + lane]), acc0);
        }
    }

    float res = alpha * ((acc0 + acc1) + (acc2 + acc3));
    if (beta != 0.f) res -= beta * __half2float(prev[(size_t)wid * F + lane]);
    dst[(size_t)wid * F + lane] = __float2half(res);
}

// ---------------- fused MFMA: y = softmax(relu(sum_k Tk@W1k + b1) @ W2 + b2) ----------------
__global__ __launch_bounds__(256) void k_fused_mfma(const __half* __restrict__ T,
                                                    const __half* __restrict__ Wf,
                                                    const float* __restrict__ b1,
                                                    const float* __restrict__ W2,
                                                    const float* __restrict__ b2,
                                                    float* __restrict__ y) {
    __shared__ float Ht[64][65];
    __shared__ float W2l[64 * 16];
    __shared__ float b2l[16];
    int tid = threadIdx.x;
    int lane = tid & 63;
    int w = tid >> 6;
    int ln15 = lane & 15;
    int lg = lane >> 4;
    int base = blockIdx.x * 64;

    for (int j = tid; j < 64 * 16; j += 256) W2l[j] = W2[j];
    if (tid < 16) b2l[tid] = b2[tid];

    int nd = base + (w << 4) + ln15;
    if (nd > N_NODES - 1) nd = N_NODES - 1;  // clamp: garbage rows, stores guarded

    f32x4 acc0 = {0.f, 0.f, 0.f, 0.f};
    f32x4 acc1 = {0.f, 0.f, 0.f, 0.f};
    f32x4 acc2 = {0.f, 0.f, 0.f, 0.f};
    f32x4 acc3 = {0.f, 0.f, 0.f, 0.f};

    for (int s = 0; s < 16; s++) {
        int kidx = s >> 1;
        int fg = s & 1;
        f16x8 a = *(const f16x8*)(T + ((size_t)kidx * N_NODES + nd) * F + fg * 32 + lg * 8);
        const __half* wb = Wf + ((size_t)((kidx * 2 + fg) * 4) * 64 + lane) * 8;
        f16x8 b0 = *(const f16x8*)(wb);
        f16x8 b1f = *(const f16x8*)(wb + 64 * 8);
        f16x8 b2f = *(const f16x8*)(wb + 128 * 8);
        f16x8 b3f = *(const f16x8*)(wb + 192 * 8);
        acc0 = __builtin_amdgcn_mfma_f32_16x16x32_f16(a, b0, acc0, 0, 0, 0);
        acc1 = __builtin_amdgcn_mfma_f32_16x16x32_f16(a, b1f, acc1, 0, 0, 0);
        acc2 = __builtin_amdgcn_mfma_f32_16x16x32_f16(a, b2f, acc2, 0, 0, 0);
        acc3 = __builtin_amdgcn_mfma_f32_16x16x32_f16(a, b3f, acc3, 0, 0, 0);
    }

    int hrow = (w << 4) + (lg << 2);
    {
        float bb0 = b1[0 * 16 + ln15];
        float bb1 = b1[1 * 16 + ln15];
        float bb2 = b1[2 * 16 + ln15];
        float bb3 = b1[3 * 16 + ln15];
#pragma unroll
        for (int r = 0; r < 4; r++) {
            float h0 = acc0[r] + bb0;
            float h1 = acc1[r] + bb1;
            float h2 = acc2[r] + bb2;
            float h3 = acc3[r] + bb3;
            Ht[hrow + r][0 * 16 + ln15] = h0 > 0.f ? h0 : 0.f;
            Ht[hrow + r][1 * 16 + ln15] = h1 > 0.f ? h1 : 0.f;
            Ht[hrow + r][2 * 16 + ln15] = h2 > 0.f ? h2 : 0.f;
            Ht[hrow + r][3 * 16 + ln15] = h3 > 0.f ? h3 : 0.f;
        }
    }
    __syncthreads();

    int node = tid >> 2;
    int cg = tid & 3;
    int gnode = base + node;
    if (gnode >= N_NODES) return;
    float l0 = b2l[cg * 4 + 0], l1 = b2l[cg * 4 + 1], l2 = b2l[cg * 4 + 2], l3 = b2l[cg * 4 + 3];
    for (int f = 0; f < 64; f++) {
        float h = Ht[node][f];
        l0 = fmaf(h, W2l[f * 16 + cg * 4 + 0], l0);
        l1 = fmaf(h, W2l[f * 16 + cg * 4 + 1], l1);
        l2 = fmaf(h, W2l[f * 16 + cg * 4 + 2], l2);
        l3 = fmaf(h, W2l[f * 16 + cg * 4 + 3], l3);
    }
    float m = fmaxf(fmaxf(l0, l1), fmaxf(l2, l3));
    m = fmaxf(m, __shfl_xor(m, 1, 64));
    m = fmaxf(m, __shfl_xor(m, 2, 64));
    float e0 = expf(l0 - m), e1 = expf(l1 - m), e2 = expf(l2 - m), e3 = expf(l3 - m);
    float s = e0 + e1 + e2 + e3;
    s += __shfl_xor(s, 1, 64);
    s += __shfl_xor(s, 2, 64);
    float inv = 1.f / s;
    float4 o = make_float4(e0 * inv, e1 * inv, e2 * inv, e3 * inv);
    *(float4*)&y[(size_t)gnode * 16 + cg * 4] = o;
}

// ---------------- launch ----------------

extern "C" void kernel_launch(void* const* d_in, const int* in_sizes, int n_in,
                              void* d_out, int out_size, void* d_ws, size_t ws_size,
                              hipStream_t stream) {
    const float* x  = (const float*)d_in[0];
    const int*   ei = (const int*)d_in[1];
    const float* W1 = (const float*)d_in[2];
    const float* b1 = (const float*)d_in[3];
    const float* W2 = (const float*)d_in[4];
    const float* b2 = (const float*)d_in[5];
    float* y = (float*)d_out;

    char* p = (char*)d_ws;
    auto alloc = [&](size_t bytes) {
        char* q = p;
        p += (bytes + 255) & ~(size_t)255;
        return q;
    };
    int*   deg    = (int*)alloc((size_t)N_NODES * 4);
    float* dinv   = (float*)alloc((size_t)N_NODES * 4);
    int*   rowptr = (int*)alloc((size_t)(N_NODES + 1) * 4);
    int*   bsum   = (int*)alloc(128 * 4);
    int*   gcur   = (int*)alloc(64 * 4);
    int2*  csr_ew = (int2*)alloc((size_t)N_EDGES * 8);
    __half* T     = (__half*)alloc((size_t)K1 * N_NODES * F * 2);
    __half* Wf    = (__half*)alloc((size_t)K1 * 2 * 4 * 64 * 8 * 2);

    // bucket buffer (14.5 MB) aliases T: dead before k_cvt/k_prop write T.
    int2* bk = (int2*)T;

    hipMemsetAsync(gcur, 0, 64 * 4, stream);

    int nb = (N_NODES + 255) / 256;
    k_bucketA<<<(N_EDGES + 1023) / 1024, 256, 0, stream>>>(ei, gcur, bk);
    k_degB<<<NBK, 256, 0, stream>>>(bk, gcur, deg);
    k_dinv<<<nb, 256, 0, stream>>>(deg, dinv);
    int nblk = (N_NODES + 1023) / 1024;
    k_scan1<<<nblk, 256, 0, stream>>>(deg, rowptr, bsum);
    k_scan2<<<1, 64, 0, stream>>>(bsum, rowptr, nblk);
    k_scan3<<<nblk, 256, 0, stream>>>(rowptr, bsum);
    k_fillB<<<NBK, 256, 0, stream>>>(bk, gcur, rowptr, dinv, csr_ew);
    k_prepW<<<16, 256, 0, stream>>>(W1, Wf);

    const size_t TSZ = (size_t)N_NODES * F;
    __half* Tk[K1];
    for (int k = 0; k < K1; k++) Tk[k] = T + (size_t)k * TSZ;

    k_cvt<<<(N_NODES * F / 4 + 255) / 256, 256, 0, stream>>>(x, Tk[0]);

    int prop_blocks = (N_NODES + 3) / 4;
    k_prop<<<prop_blocks, 256, 0, stream>>>(rowptr, csr_ew, Tk[0], Tk[0], Tk[1], 1.f, 0.f);
    for (int k = 2; k < K1; k++)
        k_prop<<<prop_blocks, 256, 0, stream>>>(rowptr, csr_ew, Tk[k - 1], Tk[k - 2], Tk[k], 2.f, 1.f);

    int gemm_blocks = (N_NODES + 63) / 64;
    k_fused_mfma<<<gemm_blocks, 256, 0, stream>>>(T, Wf, b1, W2, b2, y);
}